// Round 6
// baseline (529.512 us; speedup 1.0000x reference)
//
#include <hip/hip_runtime.h>
#include <hip/hip_bf16.h>

typedef __hip_bfloat16 bf16;
using bf16x8 = __attribute__((ext_vector_type(8))) short;
using f32x4  = __attribute__((ext_vector_type(4))) float;

#define C_DIM 512
#define L_DIM 2048
#define B_DIM 8

#define MFMA16(a, b, c) __builtin_amdgcn_mfma_f32_16x16x32_bf16(a, b, c, 0, 0, 0)

__device__ __forceinline__ short f2bf_s(float f) {
    bf16 h = __float2bfloat16(f);
    return *reinterpret_cast<short*>(&h);
}

// ---- workspace layout (bytes) ----
static const size_t OFF_XT  = 0;                      // 16 MB
static const size_t OFF_WQB = 16777216;
static const size_t OFF_WKB = 16842752;
static const size_t OFF_WVB = 16908288;
static const size_t OFF_WOB = 17432576;
static const size_t OFF_QT  = 17956864;
static const size_t OFF_KT  = 20054016;
static const size_t OFF_VT  = 22151168;
static const size_t OFF_O1  = 38928384;

// ---------------- K0a: weights fp32 -> bf16 ----------------
__global__ void k_wcvt(const float* __restrict__ Wq, const float* __restrict__ Wk,
                       const float* __restrict__ Wv, const float* __restrict__ Wo,
                       bf16* __restrict__ Wqb, bf16* __restrict__ Wkb,
                       bf16* __restrict__ Wvb, bf16* __restrict__ Wob) {
    int i = blockIdx.x * 256 + threadIdx.x;
    if (i < 32768)        Wqb[i]          = __float2bfloat16(Wq[i]);
    else if (i < 65536)   Wkb[i - 32768]  = __float2bfloat16(Wk[i - 32768]);
    else if (i < 327680)  Wvb[i - 65536]  = __float2bfloat16(Wv[i - 65536]);
    else                  Wob[i - 327680] = __float2bfloat16(Wo[i - 327680]);
}

// ---------------- K0b: transpose x [B][C][L] fp32 -> xT [B][L][C] bf16 ----------------
__global__ __launch_bounds__(256) void k_tr(const float* __restrict__ x,
                                            bf16* __restrict__ xT) {
    __shared__ float T[64][65];
    const int b = blockIdx.z;
    const int l0 = blockIdx.x * 64, c0 = blockIdx.y * 64;
    const int tx = threadIdx.x & 63, ty = threadIdx.x >> 6;

    const float* xp = x + ((size_t)b * C_DIM + c0) * L_DIM + l0;
#pragma unroll
    for (int i = 0; i < 16; ++i) {
        int c = i * 4 + ty;
        T[c][tx] = xp[(size_t)c * L_DIM + tx];
    }
    __syncthreads();
#pragma unroll
    for (int i = 0; i < 16; ++i) {
        int l = i * 4 + ty;
        xT[((size_t)b * L_DIM + l0 + l) * C_DIM + c0 + tx] = __float2bfloat16(T[tx][l]);
    }
}

// ---------------- K1: QKV projection via MFMA (reg-prefetched K-loop) ----------------
__global__ __launch_bounds__(256, 2) void k_qkv(const bf16* __restrict__ xT,
                                                const bf16* __restrict__ Wqb, const float* __restrict__ bq,
                                                const bf16* __restrict__ Wkb, const float* __restrict__ bk,
                                                const bf16* __restrict__ Wvb, const float* __restrict__ bv,
                                                bf16* __restrict__ qT, bf16* __restrict__ kT,
                                                bf16* __restrict__ vTT) {
    const int b = blockIdx.z, y = blockIdx.y, bx = blockIdx.x;
    const int tid = threadIdx.x;
    const int w = tid >> 6, lane = tid & 63, quad = lane >> 4, l15 = lane & 15;
    const int wm = w >> 1, wn = w & 1;
    const size_t bL = (size_t)b * L_DIM;

    f32x4 acc[4][4];
#pragma unroll
    for (int i = 0; i < 4; ++i)
#pragma unroll
        for (int j = 0; j < 4; ++j) acc[i][j] = (f32x4){0.f, 0.f, 0.f, 0.f};

    const bf16* arow[4];
    const bf16* brow[4];
    if (y == 0) {
        const int mbase = bx * 128 + wm * 64;
        const bf16* Wb = wn ? Wkb : Wqb;
#pragma unroll
        for (int mi = 0; mi < 4; ++mi) arow[mi] = xT + (bL + mbase + mi * 16 + l15) * C_DIM;
#pragma unroll
        for (int ni = 0; ni < 4; ++ni) brow[ni] = Wb + (size_t)(ni * 16 + l15) * C_DIM;
    } else {
        const int cbase = (y - 1) * 128 + wm * 64;
        const int lbase = bx * 128 + wn * 64;
#pragma unroll
        for (int mi = 0; mi < 4; ++mi) arow[mi] = Wvb + (size_t)(cbase + mi * 16 + l15) * C_DIM;
#pragma unroll
        for (int ni = 0; ni < 4; ++ni) brow[ni] = xT + (bL + lbase + ni * 16 + l15) * C_DIM;
    }

    bf16x8 af[4], bfr[4], afn[4], bfn[4];
    {
        const int ko = quad * 8;
#pragma unroll
        for (int mi = 0; mi < 4; ++mi) af[mi] = *(const bf16x8*)(arow[mi] + ko);
#pragma unroll
        for (int ni = 0; ni < 4; ++ni) bfr[ni] = *(const bf16x8*)(brow[ni] + ko);
    }
    for (int kt = 0; kt < 16; ++kt) {
        if (kt < 15) {
            const int ko = (kt + 1) * 32 + quad * 8;
#pragma unroll
            for (int mi = 0; mi < 4; ++mi) afn[mi] = *(const bf16x8*)(arow[mi] + ko);
#pragma unroll
            for (int ni = 0; ni < 4; ++ni) bfn[ni] = *(const bf16x8*)(brow[ni] + ko);
        }
#pragma unroll
        for (int mi = 0; mi < 4; ++mi)
#pragma unroll
            for (int ni = 0; ni < 4; ++ni)
                acc[mi][ni] = MFMA16(af[mi], bfr[ni], acc[mi][ni]);
#pragma unroll
        for (int i = 0; i < 4; ++i) { af[i] = afn[i]; bfr[i] = bfn[i]; }
    }

    if (y == 0) {
        const int mbase = bx * 128 + wm * 64;
        const float* bias = wn ? bk : bq;
        bf16* dst = wn ? kT : qT;
        float bb[4];
#pragma unroll
        for (int ni = 0; ni < 4; ++ni) bb[ni] = bias[ni * 16 + l15];
#pragma unroll
        for (int mi = 0; mi < 4; ++mi)
#pragma unroll
            for (int r = 0; r < 4; ++r) {
                int l = mbase + mi * 16 + quad * 4 + r;
#pragma unroll
                for (int ni = 0; ni < 4; ++ni)
                    dst[(bL + l) * 64 + ni * 16 + l15] = __float2bfloat16(acc[mi][ni][r] + bb[ni]);
            }
    } else {
        const int cbase = (y - 1) * 128 + wm * 64;
        const int lbase = bx * 128 + wn * 64;
#pragma unroll
        for (int mi = 0; mi < 4; ++mi)
#pragma unroll
            for (int r = 0; r < 4; ++r) {
                int c = cbase + mi * 16 + quad * 4 + r;
                float bb = bv[c];
#pragma unroll
                for (int ni = 0; ni < 4; ++ni)
                    vTT[((size_t)b * C_DIM + c) * L_DIM + lbase + ni * 16 + l15] =
                        __float2bfloat16(acc[mi][ni][r] + bb);
            }
    }
}

// ---------------- K2: barrier-free MFMA attention ----------------
// grid 1024 = 8 b (fast, XCD pin) x 4 c-splits x 32 q-blocks. block 256 = 4 waves.
// Wave w owns q rows q0+w*16..+15 END-TO-END: scores (own rows, all k), softmax
// sums (shfl-reduce, wave-local), PV over the block's 128-c slice. P transposes
// C-layout -> A-layout through a PER-WAVE LDS scratch: ds_write -> lgkm wait ->
// ds_read within one wave needs NO barrier. Zero __syncthreads in the K-loop.
// All 4 waves load identical K/V fragments (L1-served).
__global__ __launch_bounds__(256, 4) void k_attn(const bf16* __restrict__ qT,
                                                 const bf16* __restrict__ kT,
                                                 const bf16* __restrict__ vTT,
                                                 bf16* __restrict__ o1) {
    const int bid = blockIdx.x;
    const int b = bid & 7;
    const int cs = (bid >> 3) & 3;
    const int q0 = (bid >> 5) * 64;
    const int c0 = cs * 128;
    const int tid = threadIdx.x;
    const int w = tid >> 6, lane = tid & 63;
    const int quad = lane >> 4, l15 = lane & 15;
    const float scale = 0.125f;

    __shared__ short scr[4][16 * 40];     // per-wave P scratch, pitch 40 shorts

    const size_t bL = (size_t)b * L_DIM;

    // Q A-frags for this wave's 16 rows (m=l15, k=quad*8+j)
    const bf16* qrow = qT + (bL + q0 + w * 16 + l15) * 64;
    bf16x8 qf0 = *(const bf16x8*)(qrow + quad * 8);
    bf16x8 qf1 = *(const bf16x8*)(qrow + 32 + quad * 8);

    f32x4 acc[8];
#pragma unroll
    for (int cg = 0; cg < 8; ++cg) acc[cg] = (f32x4){0.f, 0.f, 0.f, 0.f};
    float ssum[4] = {0.f, 0.f, 0.f, 0.f};

    const bf16* kb = kT + bL * 64;
    const bf16* vb = vTT + ((size_t)b * C_DIM + c0) * L_DIM;
    short* myscr = scr[w];

    for (int t = 0; t < 64; ++t) {
        const int k0 = t * 32;
        // K B-frags (rows k0+kh*16+l15) and V B-frags (rows c0+cg*16+l15, k=k0+quad*8)
        bf16x8 kf[2][2];
#pragma unroll
        for (int kh = 0; kh < 2; ++kh)
#pragma unroll
            for (int h2 = 0; h2 < 2; ++h2)
                kf[kh][h2] = *(const bf16x8*)(kb + (size_t)(k0 + kh * 16 + l15) * 64 + h2 * 32 + quad * 8);
        bf16x8 vf[8];
#pragma unroll
        for (int cg = 0; cg < 8; ++cg)
            vf[cg] = *(const bf16x8*)(vb + (size_t)(cg * 16 + l15) * L_DIM + k0 + quad * 8);

        // scores for own 16 q x 32 k, exp, stash C-layout into per-wave scratch
#pragma unroll
        for (int kh = 0; kh < 2; ++kh) {
            f32x4 s = {0.f, 0.f, 0.f, 0.f};
            s = MFMA16(qf0, kf[kh][0], s);
            s = MFMA16(qf1, kf[kh][1], s);
#pragma unroll
            for (int r = 0; r < 4; ++r) {
                float p = __expf(fminf(s[r] * scale, 60.f) - 4.f);
                short pb = f2bf_s(p);
                bf16 pbh = *reinterpret_cast<bf16*>(&pb);
                ssum[r] += __bfloat162float(pbh);
                myscr[(quad * 4 + r) * 40 + kh * 16 + l15] = pb;
            }
        }
        // wave-synchronous transpose read (A-layout): row l15, k = quad*8..+7
        bf16x8 pf = *(const bf16x8*)&myscr[l15 * 40 + quad * 8];
#pragma unroll
        for (int cg = 0; cg < 8; ++cg)
            acc[cg] = MFMA16(pf, vf[cg], acc[cg]);
    }

    // S over the 16 columns (lane bits 0-3); each lane keeps rows quad*4+r
#pragma unroll
    for (int off = 1; off < 16; off <<= 1)
#pragma unroll
        for (int r = 0; r < 4; ++r) ssum[r] += __shfl_xor(ssum[r], off, 64);
    float inv[4];
#pragma unroll
    for (int r = 0; r < 4; ++r) inv[r] = 1.f / ssum[r];

    // epilogue: D[q local][c] C-layout (row=quad*4+r, col=cg*16+l15) -> o1[b][q][c]
#pragma unroll
    for (int r = 0; r < 4; ++r) {
        const size_t base = (bL + q0 + w * 16 + quad * 4 + r) * C_DIM + c0;
#pragma unroll
        for (int cg = 0; cg < 8; ++cg)
            o1[base + cg * 16 + l15] = __float2bfloat16(acc[cg][r] * inv[r]);
    }
}

// ---------------- K3: Wo GEMM + bias + residual via MFMA (reg-prefetched) ----------------
__global__ __launch_bounds__(256, 2) void k_out(const float* __restrict__ x,
                                                const bf16* __restrict__ Wob,
                                                const float* __restrict__ bo,
                                                const bf16* __restrict__ o1,
                                                float* __restrict__ out) {
    const int b = blockIdx.z;
    const int tid = threadIdx.x;
    const int w = tid >> 6, lane = tid & 63, quad = lane >> 4, l15 = lane & 15;
    const int wm = w >> 1, wn = w & 1;
    const int mbase = blockIdx.y * 128 + wm * 64;
    const int nbase = blockIdx.x * 128 + wn * 64;
    const size_t bL = (size_t)b * L_DIM;

    f32x4 acc[4][4];
#pragma unroll
    for (int i = 0; i < 4; ++i)
#pragma unroll
        for (int j = 0; j < 4; ++j) acc[i][j] = (f32x4){0.f, 0.f, 0.f, 0.f};

    const bf16* arow[4];
    const bf16* brow[4];
#pragma unroll
    for (int mi = 0; mi < 4; ++mi) arow[mi] = Wob + (size_t)(mbase + mi * 16 + l15) * C_DIM;
#pragma unroll
    for (int ni = 0; ni < 4; ++ni) brow[ni] = o1 + (bL + nbase + ni * 16 + l15) * C_DIM;

    bf16x8 af[4], bfr[4], afn[4], bfn[4];
    {
        const int ko = quad * 8;
#pragma unroll
        for (int mi = 0; mi < 4; ++mi) af[mi] = *(const bf16x8*)(arow[mi] + ko);
#pragma unroll
        for (int ni = 0; ni < 4; ++ni) bfr[ni] = *(const bf16x8*)(brow[ni] + ko);
    }
    for (int kt = 0; kt < 16; ++kt) {
        if (kt < 15) {
            const int ko = (kt + 1) * 32 + quad * 8;
#pragma unroll
            for (int mi = 0; mi < 4; ++mi) afn[mi] = *(const bf16x8*)(arow[mi] + ko);
#pragma unroll
            for (int ni = 0; ni < 4; ++ni) bfn[ni] = *(const bf16x8*)(brow[ni] + ko);
        }
#pragma unroll
        for (int mi = 0; mi < 4; ++mi)
#pragma unroll
            for (int ni = 0; ni < 4; ++ni)
                acc[mi][ni] = MFMA16(af[mi], bfr[ni], acc[mi][ni]);
#pragma unroll
        for (int i = 0; i < 4; ++i) { af[i] = afn[i]; bfr[i] = bfn[i]; }
    }

#pragma unroll
    for (int mi = 0; mi < 4; ++mi)
#pragma unroll
        for (int r = 0; r < 4; ++r) {
            int row = mbase + mi * 16 + quad * 4 + r;
            float bb = bo[row];
            size_t base = ((size_t)b * C_DIM + row) * L_DIM + nbase;
#pragma unroll
            for (int ni = 0; ni < 4; ++ni) {
                size_t idx = base + ni * 16 + l15;
                out[idx] = acc[mi][ni][r] + bb + x[idx];
            }
        }
}

extern "C" void kernel_launch(void* const* d_in, const int* in_sizes, int n_in,
                              void* d_out, int out_size, void* d_ws, size_t ws_size,
                              hipStream_t stream) {
    const float* x  = (const float*)d_in[0];
    const float* Wq = (const float*)d_in[1];
    const float* bq = (const float*)d_in[2];
    const float* Wk = (const float*)d_in[3];
    const float* bk = (const float*)d_in[4];
    const float* Wv = (const float*)d_in[5];
    const float* bv = (const float*)d_in[6];
    const float* Wo = (const float*)d_in[7];
    const float* bo = (const float*)d_in[8];

    char* wsb = (char*)d_ws;
    bf16* xT  = (bf16*)(wsb + OFF_XT);
    bf16* Wqb = (bf16*)(wsb + OFF_WQB);
    bf16* Wkb = (bf16*)(wsb + OFF_WKB);
    bf16* Wvb = (bf16*)(wsb + OFF_WVB);
    bf16* Wob = (bf16*)(wsb + OFF_WOB);
    bf16* qT  = (bf16*)(wsb + OFF_QT);
    bf16* kT  = (bf16*)(wsb + OFF_KT);
    bf16* vTT = (bf16*)(wsb + OFF_VT);
    bf16* o1  = (bf16*)(wsb + OFF_O1);
    float* out = (float*)d_out;

    k_wcvt<<<dim3(2304), 256, 0, stream>>>(Wq, Wk, Wv, Wo, Wqb, Wkb, Wvb, Wob);
    k_tr<<<dim3(L_DIM / 64, C_DIM / 64, B_DIM), 256, 0, stream>>>(x, xT);
    k_qkv<<<dim3(16, 5, B_DIM), 256, 0, stream>>>(xT, Wqb, bq, Wkb, bk, Wvb, bv, qT, kT, vTT);
    k_attn<<<dim3(1024), 256, 0, stream>>>(qT, kT, vTT, o1);
    k_out<<<dim3(16, 4, B_DIM), 256, 0, stream>>>(x, Wob, bo, o1, out);
}

// Round 7
// 361.219 us; speedup vs baseline: 1.4659x; 1.4659x over previous
//
#include <hip/hip_runtime.h>
#include <hip/hip_bf16.h>

typedef __hip_bfloat16 bf16;
using bf16x8 = __attribute__((ext_vector_type(8))) short;
using f32x4  = __attribute__((ext_vector_type(4))) float;

#define C_DIM 512
#define L_DIM 2048
#define B_DIM 8

#define MFMA16(a, b, c) __builtin_amdgcn_mfma_f32_16x16x32_bf16(a, b, c, 0, 0, 0)

// q pre-scaled by CQK^-0.5 * log2(e) so scores are in exp2 domain
#define Q_PRESCALE 0.18033688011112042f

__device__ __forceinline__ short f2bf_s(float f) {
    bf16 h = __float2bfloat16(f);
    return *reinterpret_cast<short*>(&h);
}

// ---- workspace layout (bytes) ----
static const size_t OFF_XT  = 0;                      // 16 MB
static const size_t OFF_WQB = 16777216;
static const size_t OFF_WKB = 16842752;
static const size_t OFF_WVB = 16908288;
static const size_t OFF_WOB = 17432576;
static const size_t OFF_QT  = 17956864;
static const size_t OFF_KT  = 20054016;
static const size_t OFF_VT  = 22151168;
static const size_t OFF_O1  = 38928384;

// ---------------- K0a: weights fp32 -> bf16 ----------------
__global__ void k_wcvt(const float* __restrict__ Wq, const float* __restrict__ Wk,
                       const float* __restrict__ Wv, const float* __restrict__ Wo,
                       bf16* __restrict__ Wqb, bf16* __restrict__ Wkb,
                       bf16* __restrict__ Wvb, bf16* __restrict__ Wob) {
    int i = blockIdx.x * 256 + threadIdx.x;
    if (i < 32768)        Wqb[i]          = __float2bfloat16(Wq[i]);
    else if (i < 65536)   Wkb[i - 32768]  = __float2bfloat16(Wk[i - 32768]);
    else if (i < 327680)  Wvb[i - 65536]  = __float2bfloat16(Wv[i - 65536]);
    else                  Wob[i - 327680] = __float2bfloat16(Wo[i - 327680]);
}

// ---------------- K0b: transpose x [B][C][L] fp32 -> xT [B][L][C] bf16 ----------------
__global__ __launch_bounds__(256) void k_tr(const float* __restrict__ x,
                                            bf16* __restrict__ xT) {
    __shared__ float T[64][65];
    const int b = blockIdx.z;
    const int l0 = blockIdx.x * 64, c0 = blockIdx.y * 64;
    const int tx = threadIdx.x & 63, ty = threadIdx.x >> 6;

    const float* xp = x + ((size_t)b * C_DIM + c0) * L_DIM + l0;
#pragma unroll
    for (int i = 0; i < 16; ++i) {
        int c = i * 4 + ty;
        T[c][tx] = xp[(size_t)c * L_DIM + tx];
    }
    __syncthreads();
#pragma unroll
    for (int i = 0; i < 16; ++i) {
        int l = i * 4 + ty;
        xT[((size_t)b * L_DIM + l0 + l) * C_DIM + c0 + tx] = __float2bfloat16(T[tx][l]);
    }
}

// ---------------- K1: QKV projection via MFMA (reg-prefetched K-loop) ----------------
// q output is pre-scaled by Q_PRESCALE (softmax-invariant; k_attn uses exp2).
__global__ __launch_bounds__(256, 2) void k_qkv(const bf16* __restrict__ xT,
                                                const bf16* __restrict__ Wqb, const float* __restrict__ bq,
                                                const bf16* __restrict__ Wkb, const float* __restrict__ bk,
                                                const bf16* __restrict__ Wvb, const float* __restrict__ bv,
                                                bf16* __restrict__ qT, bf16* __restrict__ kT,
                                                bf16* __restrict__ vTT) {
    const int b = blockIdx.z, y = blockIdx.y, bx = blockIdx.x;
    const int tid = threadIdx.x;
    const int w = tid >> 6, lane = tid & 63, quad = lane >> 4, l15 = lane & 15;
    const int wm = w >> 1, wn = w & 1;
    const size_t bL = (size_t)b * L_DIM;

    f32x4 acc[4][4];
#pragma unroll
    for (int i = 0; i < 4; ++i)
#pragma unroll
        for (int j = 0; j < 4; ++j) acc[i][j] = (f32x4){0.f, 0.f, 0.f, 0.f};

    const bf16* arow[4];
    const bf16* brow[4];
    if (y == 0) {
        const int mbase = bx * 128 + wm * 64;
        const bf16* Wb = wn ? Wkb : Wqb;
#pragma unroll
        for (int mi = 0; mi < 4; ++mi) arow[mi] = xT + (bL + mbase + mi * 16 + l15) * C_DIM;
#pragma unroll
        for (int ni = 0; ni < 4; ++ni) brow[ni] = Wb + (size_t)(ni * 16 + l15) * C_DIM;
    } else {
        const int cbase = (y - 1) * 128 + wm * 64;
        const int lbase = bx * 128 + wn * 64;
#pragma unroll
        for (int mi = 0; mi < 4; ++mi) arow[mi] = Wvb + (size_t)(cbase + mi * 16 + l15) * C_DIM;
#pragma unroll
        for (int ni = 0; ni < 4; ++ni) brow[ni] = xT + (bL + lbase + ni * 16 + l15) * C_DIM;
    }

    bf16x8 af[4], bfr[4], afn[4], bfn[4];
    {
        const int ko = quad * 8;
#pragma unroll
        for (int mi = 0; mi < 4; ++mi) af[mi] = *(const bf16x8*)(arow[mi] + ko);
#pragma unroll
        for (int ni = 0; ni < 4; ++ni) bfr[ni] = *(const bf16x8*)(brow[ni] + ko);
    }
    for (int kt = 0; kt < 16; ++kt) {
        if (kt < 15) {
            const int ko = (kt + 1) * 32 + quad * 8;
#pragma unroll
            for (int mi = 0; mi < 4; ++mi) afn[mi] = *(const bf16x8*)(arow[mi] + ko);
#pragma unroll
            for (int ni = 0; ni < 4; ++ni) bfn[ni] = *(const bf16x8*)(brow[ni] + ko);
        }
#pragma unroll
        for (int mi = 0; mi < 4; ++mi)
#pragma unroll
            for (int ni = 0; ni < 4; ++ni)
                acc[mi][ni] = MFMA16(af[mi], bfr[ni], acc[mi][ni]);
#pragma unroll
        for (int i = 0; i < 4; ++i) { af[i] = afn[i]; bfr[i] = bfn[i]; }
    }

    if (y == 0) {
        const int mbase = bx * 128 + wm * 64;
        const float* bias = wn ? bk : bq;
        bf16* dst = wn ? kT : qT;
        const float osc = wn ? 1.f : Q_PRESCALE;
        float bb[4];
#pragma unroll
        for (int ni = 0; ni < 4; ++ni) bb[ni] = bias[ni * 16 + l15];
#pragma unroll
        for (int mi = 0; mi < 4; ++mi)
#pragma unroll
            for (int r = 0; r < 4; ++r) {
                int l = mbase + mi * 16 + quad * 4 + r;
#pragma unroll
                for (int ni = 0; ni < 4; ++ni)
                    dst[(bL + l) * 64 + ni * 16 + l15] =
                        __float2bfloat16((acc[mi][ni][r] + bb[ni]) * osc);
            }
    } else {
        const int cbase = (y - 1) * 128 + wm * 64;
        const int lbase = bx * 128 + wn * 64;
#pragma unroll
        for (int mi = 0; mi < 4; ++mi)
#pragma unroll
            for (int r = 0; r < 4; ++r) {
                int c = cbase + mi * 16 + quad * 4 + r;
                float bb = bv[c];
#pragma unroll
                for (int ni = 0; ni < 4; ++ni)
                    vTT[((size_t)b * C_DIM + c) * L_DIM + lbase + ni * 16 + l15] =
                        __float2bfloat16(acc[mi][ni][r] + bb);
            }
    }
}

// ---------------- K2: MFMA attention, block-shared P, c-split 4 ----------------
// grid 1024 = 8 b (fast, XCD pin) x 4 c-splits x 32 q-blocks. block 256 = 4 waves.
// Wave w: scores for q rows w*16..+15 (shared via LDS P, once per block), PV for
// its 32-c slice of the block's 128 c. One barrier per 32-k tile (double-buffered P).
// Scores already in exp2 domain (q pre-scaled): p = exp2(s - 4).
__global__ __launch_bounds__(256, 3) void k_attn(const bf16* __restrict__ qT,
                                                 const bf16* __restrict__ kT,
                                                 const bf16* __restrict__ vTT,
                                                 bf16* __restrict__ o1) {
    const int bid = blockIdx.x;
    const int b = bid & 7;
    const int cs = (bid >> 3) & 3;
    const int q0 = (bid >> 5) * 64;
    const int c0 = cs * 128;
    const int tid = threadIdx.x;
    const int w = tid >> 6, lane = tid & 63;
    const int quad = lane >> 4, l15 = lane & 15;

    __shared__ short P[2][64 * 40];     // pitch 40 shorts
    __shared__ float S_sh[64];

    const size_t bL = (size_t)b * L_DIM;

    // Q A-frags for wave's 16 rows
    const bf16* qrow = qT + (bL + q0 + w * 16 + l15) * 64;
    bf16x8 qf0 = *(const bf16x8*)(qrow + quad * 8);
    bf16x8 qf1 = *(const bf16x8*)(qrow + 32 + quad * 8);

    f32x4 acc[4][2];
#pragma unroll
    for (int i = 0; i < 4; ++i)
#pragma unroll
        for (int j = 0; j < 2; ++j) acc[i][j] = (f32x4){0.f, 0.f, 0.f, 0.f};
    float ssum[4] = {0.f, 0.f, 0.f, 0.f};

    // V row pointers (B-frag: n=c via l15, k=l via quad); wave's 32-c slice
    const bf16* vrow[2];
#pragma unroll
    for (int cg = 0; cg < 2; ++cg)
        vrow[cg] = vTT + ((size_t)b * C_DIM + c0 + w * 32 + cg * 16 + l15) * L_DIM + quad * 8;

    const bf16* kb = kT + bL * 64;
    bf16x8 kf[2][2], kfn[2][2];
#pragma unroll
    for (int kh = 0; kh < 2; ++kh)
#pragma unroll
        for (int h2 = 0; h2 < 2; ++h2)
            kf[kh][h2] = *(const bf16x8*)(kb + (size_t)(kh * 16 + l15) * 64 + h2 * 32 + quad * 8);

    for (int t = 0; t < 64; ++t) {
        const int k0 = t * 32;
        // this tile's V loads + next tile's K loads in flight across exp+barrier
        bf16x8 vf[2];
#pragma unroll
        for (int cg = 0; cg < 2; ++cg) vf[cg] = *(const bf16x8*)(vrow[cg] + k0);
        if (t < 63) {
#pragma unroll
            for (int kh = 0; kh < 2; ++kh)
#pragma unroll
                for (int h2 = 0; h2 < 2; ++h2)
                    kfn[kh][h2] = *(const bf16x8*)(kb + (size_t)(k0 + 32 + kh * 16 + l15) * 64 + h2 * 32 + quad * 8);
        }

        short* Pb = P[t & 1];
#pragma unroll
        for (int kh = 0; kh < 2; ++kh) {
            f32x4 s = {0.f, 0.f, 0.f, 0.f};
            s = MFMA16(qf0, kf[kh][0], s);
            s = MFMA16(qf1, kf[kh][1], s);
#pragma unroll
            for (int r = 0; r < 4; ++r) {
                float p = __builtin_amdgcn_exp2f(fminf(s[r], 60.f) - 4.f);
                short pb = f2bf_s(p);
                bf16 pbh = *reinterpret_cast<bf16*>(&pb);
                ssum[r] += __bfloat162float(pbh);     // S from rounded values
                Pb[(w * 16 + quad * 4 + r) * 40 + kh * 16 + l15] = pb;
            }
        }
        __syncthreads();
        bf16x8 pf[4];
#pragma unroll
        for (int qg = 0; qg < 4; ++qg)
            pf[qg] = *(const bf16x8*)&Pb[(qg * 16 + l15) * 40 + quad * 8];
#pragma unroll
        for (int qg = 0; qg < 4; ++qg)
#pragma unroll
            for (int cg = 0; cg < 2; ++cg)
                acc[qg][cg] = MFMA16(pf[qg], vf[cg], acc[qg][cg]);
#pragma unroll
        for (int kh = 0; kh < 2; ++kh)
#pragma unroll
            for (int h2 = 0; h2 < 2; ++h2) kf[kh][h2] = kfn[kh][h2];
    }

    // reduce S over the 16 score columns (lane bits 0-3)
#pragma unroll
    for (int off = 1; off < 16; off <<= 1)
#pragma unroll
        for (int r = 0; r < 4; ++r) ssum[r] += __shfl_xor(ssum[r], off, 64);
    if (l15 == 0) {
#pragma unroll
        for (int r = 0; r < 4; ++r) S_sh[w * 16 + quad * 4 + r] = ssum[r];
    }
    __syncthreads();
    if (tid < 64) S_sh[tid] = 1.f / S_sh[tid];
    __syncthreads();

    // epilogue: normalize + write o1[b][q][c]
#pragma unroll
    for (int qg = 0; qg < 4; ++qg) {
        float inv[4];
#pragma unroll
        for (int r = 0; r < 4; ++r) inv[r] = S_sh[qg * 16 + quad * 4 + r];
#pragma unroll
        for (int r = 0; r < 4; ++r) {
            const size_t base = (bL + q0 + qg * 16 + quad * 4 + r) * C_DIM + c0 + w * 32;
#pragma unroll
            for (int cg = 0; cg < 2; ++cg)
                o1[base + cg * 16 + l15] = __float2bfloat16(acc[qg][cg][r] * inv[r]);
        }
    }
}

// ---------------- K3: Wo GEMM + bias + residual via MFMA (reg-prefetched) ----------------
__global__ __launch_bounds__(256, 2) void k_out(const float* __restrict__ x,
                                                const bf16* __restrict__ Wob,
                                                const float* __restrict__ bo,
                                                const bf16* __restrict__ o1,
                                                float* __restrict__ out) {
    const int b = blockIdx.z;
    const int tid = threadIdx.x;
    const int w = tid >> 6, lane = tid & 63, quad = lane >> 4, l15 = lane & 15;
    const int wm = w >> 1, wn = w & 1;
    const int mbase = blockIdx.y * 128 + wm * 64;
    const int nbase = blockIdx.x * 128 + wn * 64;
    const size_t bL = (size_t)b * L_DIM;

    f32x4 acc[4][4];
#pragma unroll
    for (int i = 0; i < 4; ++i)
#pragma unroll
        for (int j = 0; j < 4; ++j) acc[i][j] = (f32x4){0.f, 0.f, 0.f, 0.f};

    const bf16* arow[4];
    const bf16* brow[4];
#pragma unroll
    for (int mi = 0; mi < 4; ++mi) arow[mi] = Wob + (size_t)(mbase + mi * 16 + l15) * C_DIM;
#pragma unroll
    for (int ni = 0; ni < 4; ++ni) brow[ni] = o1 + (bL + nbase + ni * 16 + l15) * C_DIM;

    bf16x8 af[4], bfr[4], afn[4], bfn[4];
    {
        const int ko = quad * 8;
#pragma unroll
        for (int mi = 0; mi < 4; ++mi) af[mi] = *(const bf16x8*)(arow[mi] + ko);
#pragma unroll
        for (int ni = 0; ni < 4; ++ni) bfr[ni] = *(const bf16x8*)(brow[ni] + ko);
    }
    for (int kt = 0; kt < 16; ++kt) {
        if (kt < 15) {
            const int ko = (kt + 1) * 32 + quad * 8;
#pragma unroll
            for (int mi = 0; mi < 4; ++mi) afn[mi] = *(const bf16x8*)(arow[mi] + ko);
#pragma unroll
            for (int ni = 0; ni < 4; ++ni) bfn[ni] = *(const bf16x8*)(brow[ni] + ko);
        }
#pragma unroll
        for (int mi = 0; mi < 4; ++mi)
#pragma unroll
            for (int ni = 0; ni < 4; ++ni)
                acc[mi][ni] = MFMA16(af[mi], bfr[ni], acc[mi][ni]);
#pragma unroll
        for (int i = 0; i < 4; ++i) { af[i] = afn[i]; bfr[i] = bfn[i]; }
    }

#pragma unroll
    for (int mi = 0; mi < 4; ++mi)
#pragma unroll
        for (int r = 0; r < 4; ++r) {
            int row = mbase + mi * 16 + quad * 4 + r;
            float bb = bo[row];
            size_t base = ((size_t)b * C_DIM + row) * L_DIM + nbase;
#pragma unroll
            for (int ni = 0; ni < 4; ++ni) {
                size_t idx = base + ni * 16 + l15;
                out[idx] = acc[mi][ni][r] + bb + x[idx];
            }
        }
}

extern "C" void kernel_launch(void* const* d_in, const int* in_sizes, int n_in,
                              void* d_out, int out_size, void* d_ws, size_t ws_size,
                              hipStream_t stream) {
    const float* x  = (const float*)d_in[0];
    const float* Wq = (const float*)d_in[1];
    const float* bq = (const float*)d_in[2];
    const float* Wk = (const float*)d_in[3];
    const float* bk = (const float*)d_in[4];
    const float* Wv = (const float*)d_in[5];
    const float* bv = (const float*)d_in[6];
    const float* Wo = (const float*)d_in[7];
    const float* bo = (const float*)d_in[8];

    char* wsb = (char*)d_ws;
    bf16* xT  = (bf16*)(wsb + OFF_XT);
    bf16* Wqb = (bf16*)(wsb + OFF_WQB);
    bf16* Wkb = (bf16*)(wsb + OFF_WKB);
    bf16* Wvb = (bf16*)(wsb + OFF_WVB);
    bf16* Wob = (bf16*)(wsb + OFF_WOB);
    bf16* qT  = (bf16*)(wsb + OFF_QT);
    bf16* kT  = (bf16*)(wsb + OFF_KT);
    bf16* vTT = (bf16*)(wsb + OFF_VT);
    bf16* o1  = (bf16*)(wsb + OFF_O1);
    float* out = (float*)d_out;

    k_wcvt<<<dim3(2304), 256, 0, stream>>>(Wq, Wk, Wv, Wo, Wqb, Wkb, Wvb, Wob);
    k_tr<<<dim3(L_DIM / 64, C_DIM / 64, B_DIM), 256, 0, stream>>>(x, xT);
    k_qkv<<<dim3(16, 5, B_DIM), 256, 0, stream>>>(xT, Wqb, bq, Wkb, bk, Wvb, bv, qT, kT, vTT);
    k_attn<<<dim3(1024), 256, 0, stream>>>(qT, kT, vTT, o1);
    k_out<<<dim3(16, 4, B_DIM), 256, 0, stream>>>(x, Wob, bo, o1, out);
}